// Round 4
// baseline (3426.044 us; speedup 1.0000x reference)
//
#include <hip/hip_runtime.h>
#include <math.h>

// ---------------------------------------------------------------------------
// HFPS: CNN (4 residual blocks, circular 3x3 conv, 48x48, 64ch) ->
//       A = [[Fvv[n][:,n], Fvh_n],[-Fvh_n^T, Fhh_a]] (1048x1048 skew) ->
//       sign(Pf(A)), log|Pf(A)| + log_J
// Pfaffian via unpivoted blocked skew LDL^T with 2x2 pivots, fp64.
//   Pf = prod(t_p); log|Pf| = sum log|t_p| = 0.5*slogdet(A).
//
// R4 change (R3 post-mortem: flag-array barrier == counter barrier == 2.5 ms
// -> cost is the device-wide poll herd: ~65k agent-scope atomic loads/round
// on ~16 cache lines serializing at the coherence point and congesting the
// fabric for the work phases too):
//   - hierarchical tree barrier: 8 padded group counters (32 arrivals each)
//     -> root counter (8) -> root epoch -> 8 group epochs. ONE polling
//     thread per block, padded lines, s_sleep backoff. Device-wide poll
//     traffic drops ~250x. All else identical to R3 to isolate the effect.
//
// Workspace layout:
//   0..1215:  tree barrier (padded u32 lines: 8 grp_arrive, root_arrive,
//             root_epoch, 8 grp_epoch)
//   1280: logJ accumulator (double)
//   1536: nidx[1024] (int)
//   8192: tbuf / ybuf / hbuf0 / hbuf1 (4 x 64*2304 fp32)
//   2367488: A (1048*1048 fp64 = 8.79 MB)
// ---------------------------------------------------------------------------

#define NPIX 2304          // 48*48
#define MSZ  4608          // 2*48*48
#define NOCC 1024
#define NHID 24
#define PF_N 1048          // NOCC + 2*NHID
#define PF_BLOCKS 256

__device__ __forceinline__ float gelu_f(float v){
  // jax.nn.gelu approximate=True (tanh form)
  float v3 = v*v*v;
  return 0.5f*v*(1.0f + tanhf(0.7978845608028654f*(v + 0.044715f*v3)));
}

// ---- occupied-site indices (sorted), x[i]==1.0f exactly ----
__global__ void k_find_n(const float* __restrict__ x, int* __restrict__ nidx){
  __shared__ int cnt[256];
  __shared__ int off[256];
  int t = threadIdx.x;
  int c = 0;
  for (int k = 0; k < 18; k++) c += (x[t*18+k] == 1.0f) ? 1 : 0;
  cnt[t] = c;
  __syncthreads();
  if (t == 0){ int s = 0; for (int q=0;q<256;q++){ off[q]=s; s+=cnt[q]; } }
  __syncthreads();
  int o = off[t];
  for (int k = 0; k < 18; k++){
    int idx = t*18+k;
    if (x[idx] == 1.0f) nidx[o++] = idx;
  }
}

// ---- elementwise pre-op: t = [gelu](h*scale) ----
__global__ void k_pre(const float* __restrict__ in, float* __restrict__ outp,
                      int count, int dogelu, float scale){
  int g = blockIdx.x*256 + threadIdx.x;
  if (g >= count) return;
  float v = in[g]*scale;
  if (dogelu) v = gelu_f(v);
  outp[g] = v;
}

// ---- circular 3x3 conv, 64 out channels, fused bias/gelu/residual/scale ----
__global__ __launch_bounds__(256) void k_conv(const float* __restrict__ in,
      const float* __restrict__ wgt, const float* __restrict__ bias,
      const float* __restrict__ res, float* __restrict__ outp,
      int cin, int resmode, int dogelu, float scale){
  int c = blockIdx.x / 9;
  int p = (blockIdx.x % 9)*256 + threadIdx.x;
  int y = p / 48, x = p - y*48;
  int ym = ((y+47)%48)*48, y0 = y*48, yp = ((y+1)%48)*48;
  int xm = (x+47)%48, xq = (x+1)%48;
  float s = 0.f;
  const float* wp = wgt + c*cin*9;
  for (int ci = 0; ci < cin; ci++){
    const float* b_ = in + ci*NPIX;
    s += b_[ym+xm]*wp[0] + b_[ym+x]*wp[1] + b_[ym+xq]*wp[2]
       + b_[y0+xm]*wp[3] + b_[y0+x]*wp[4] + b_[y0+xq]*wp[5]
       + b_[yp+xm]*wp[6] + b_[yp+x]*wp[7] + b_[yp+xq]*wp[8];
    wp += 9;
  }
  if (bias) s += bias[c];
  if (dogelu) s = gelu_f(s);
  if (resmode == 1) s += res[c*NPIX + p];
  else if (resmode == 2) s += res[(c>>5)*NPIX + p];  // jnp.repeat(res,32,axis=0)
  s *= scale;
  outp[c*NPIX + p] = s;
}

// ---- log_J = sum over channels 48..63 of final h ----
__global__ void k_logJ(const float* __restrict__ hfin, double* __restrict__ acc){
  int g = blockIdx.x*256 + threadIdx.x;   // 144*256 = 36864
  double v = (double)hfin[48*NPIX + g];
  for (int o = 32; o > 0; o >>= 1) v += __shfl_down(v, o, 64);
  __shared__ double wsum[4];
  int lane = threadIdx.x & 63, wv = threadIdx.x >> 6;
  if (lane == 0) wsum[wv] = v;
  __syncthreads();
  if (threadIdx.x == 0) atomicAdd(acc, wsum[0]+wsum[1]+wsum[2]+wsum[3]);
}

// F_vh[m][r] = out[2r + (m>=2304)][m % 2304]
__device__ __forceinline__ double fvh_val(const float* h, int m, int r){
  int s = (m >= NPIX) ? 1 : 0;
  int p = m - s*NPIX;
  return (double)h[(2*r+s)*NPIX + p];
}

// ---- assemble skew matrix A (fp64) ----
__global__ void k_buildA(const float* __restrict__ Fvv, const float* __restrict__ Fhh,
                         const float* __restrict__ hfin, const int* __restrict__ nidx,
                         double* __restrict__ A){
  int g = blockIdx.x*256 + threadIdx.x;
  if (g >= PF_N*PF_N) return;
  int i = g / PF_N, j = g - i*PF_N;
  double v;
  if (i < NOCC){
    int ni = nidx[i];
    if (j < NOCC){
      int nj = nidx[j];
      v = 0.5*((double)Fvv[(size_t)ni*MSZ + nj] - (double)Fvv[(size_t)nj*MSZ + ni]);
    } else {
      v = fvh_val(hfin, ni, j - NOCC);
    }
  } else {
    int r = i - NOCC;
    if (j < NOCC){
      v = -fvh_val(hfin, nidx[j], r);
    } else {
      int r2 = j - NOCC;
      v = 0.5*((double)Fhh[r*NHID + r2] - (double)Fhh[r2*NHID + r]);
    }
  }
  A[g] = v;
}

// ---- hierarchical tree barrier, padded lines, 1 polling thread/block ----
// bar layout (u32 at byte offsets): grp_arrive[g] at 64*g (g=0..7),
// root_arrive at 512, root_epoch at 576, grp_epoch[g] at 640+64*g.
// Monotone epochs; arrival counters reset by their last arriver before the
// release store, so the reset is visible (happens-before) to all followers.
__device__ __forceinline__ void gridbar(unsigned* bar, unsigned ep){
  __syncthreads();
  if (threadIdx.x == 0){
    __builtin_amdgcn_fence(__ATOMIC_RELEASE, "agent");
    const int g = blockIdx.x & 7;
    unsigned* grp_arr = bar + 16*g;
    unsigned* root_arr = bar + 128;
    unsigned* root_ep  = bar + 144;
    unsigned* grp_ep   = bar + 160 + 16*g;
    unsigned a = __hip_atomic_fetch_add(grp_arr, 1u, __ATOMIC_ACQ_REL,
                                        __HIP_MEMORY_SCOPE_AGENT);
    if (a == 31u){
      __hip_atomic_store(grp_arr, 0u, __ATOMIC_RELAXED, __HIP_MEMORY_SCOPE_AGENT);
      unsigned r = __hip_atomic_fetch_add(root_arr, 1u, __ATOMIC_ACQ_REL,
                                          __HIP_MEMORY_SCOPE_AGENT);
      if (r == 7u){
        __hip_atomic_store(root_arr, 0u, __ATOMIC_RELAXED, __HIP_MEMORY_SCOPE_AGENT);
        __hip_atomic_store(root_ep, ep, __ATOMIC_RELEASE, __HIP_MEMORY_SCOPE_AGENT);
      } else {
        while (__hip_atomic_load(root_ep, __ATOMIC_ACQUIRE,
                                 __HIP_MEMORY_SCOPE_AGENT) < ep)
          __builtin_amdgcn_s_sleep(2);
      }
      __hip_atomic_store(grp_ep, ep, __ATOMIC_RELEASE, __HIP_MEMORY_SCOPE_AGENT);
    } else {
      while (__hip_atomic_load(grp_ep, __ATOMIC_ACQUIRE,
                               __HIP_MEMORY_SCOPE_AGENT) < ep)
        __builtin_amdgcn_s_sleep(2);
    }
    __builtin_amdgcn_fence(__ATOMIC_ACQUIRE, "agent");
  }
  __syncthreads();
}

// ---- blocked skew LDL^T (2x2 pivots, panel=32 cols), Pf accumulation ----
// Update rule (pivot step j, pivot rows r0=2j,r1=2j+1):
//   X[i][c] += (b_i*a_c - a_i*b_c)/t   with a_x = X[x][r0], b_x = X[x][r1]
// Phase D: diag 32x32 in LDS (all blocks, redundant) -> sInv, sAA/sBB history.
// Phase R: rows > panel, panel cols, 16-row LDS tiles over blocks.
// Phase T: trailing S += sum_l (b a^T - a b^T)/t_l (rank-32), all blocks.
__global__ __launch_bounds__(256) void k_pf(double* __restrict__ A,
      unsigned* __restrict__ bar, const double* __restrict__ logJ,
      float* __restrict__ outp){
  const int N = PF_N;
  const int tid = threadIdx.x;
  __shared__ double sBuf[3264];     // D[32][34] / P[16][33] / T-phase tiles
  __shared__ double sAA[16][32];    // a_c^{(j)} history
  __shared__ double sBB[16][32];    // b_c^{(j)} history
  __shared__ double sInv[16];
  __shared__ double sT[16];
  double lsum = 0.0, lsgn = 1.0;    // meaningful in block0/thread0
  unsigned ep = 0;

  for (int c0 = 0; c0 < N; c0 += 32){
    const int w  = (N - c0 < 32) ? (N - c0) : 32;
    const int np = w >> 1;

    // ---------------- phase D: redundant diagonal factorization ----------------
    {
      double* D = sBuf;  // [32][34]
      for (int idx = tid; idx < 32*32; idx += 256){
        int r = idx >> 5, c = idx & 31;
        D[r*34+c] = (r < w && c < w) ? A[(size_t)(c0+r)*N + c0 + c] : 0.0;
      }
      __syncthreads();
      for (int j = 0; j < np; j++){
        const int r0 = 2*j, r1 = 2*j+1;
        const double t = D[r0*34+r1];
        const double invt = 1.0 / t;
        if (tid == 0){ sInv[j] = invt; sT[j] = t; }
        if (tid < 32){ sAA[j][tid] = D[tid*34+r0]; sBB[j][tid] = D[tid*34+r1]; }
        // update sub-block rows/cols >= 2j+2 (reads cols r0,r1 only -> no race)
        for (int idx = tid; idx < 32*32; idx += 256){
          int r = idx >> 5, c = idx & 31;
          if (r >= 2*j+2 && c >= 2*j+2 && r < w && c < w){
            double ar = D[r*34+r0], br = D[r*34+r1];
            double ac = D[c*34+r0], bc = D[c*34+r1];
            D[r*34+c] += (br*ac - ar*bc) * invt;
          }
        }
        __syncthreads();
      }
      // parallel pivot log/sign reduction (block 0 only)
      if (blockIdx.x == 0 && tid < 64){
        double lv = 0.0; int sg = 0;
        if (tid < np){ double t = sT[tid]; lv = log(fabs(t)); sg = (t < 0.0) ? 1 : 0; }
        for (int o = 8; o > 0; o >>= 1){
          lv += __shfl_down(lv, o, 64);
          sg += __shfl_down(sg, o, 64);
        }
        if (tid == 0){ lsum += lv; if (sg & 1) lsgn = -lsgn; }
      }
    }

    const int tc0 = c0 + w;
    const int m = N - tc0;

    // ---------------- phase R: panel-column updates for trailing rows ----------
    if (m > 0){               // whenever m>0, w==32 and np==16
      double* P = sBuf;       // [16][33]
      const int nrt = (m + 15) >> 4;
      for (int item = blockIdx.x; item < nrt; item += PF_BLOCKS){
        const int i0 = tc0 + item*16;
        for (int idx = tid; idx < 16*32; idx += 256){
          int r = idx >> 5, c = idx & 31;
          int i = i0 + r;
          P[r*33+c] = (i < N) ? A[(size_t)i*N + c0 + c] : 0.0;
        }
        __syncthreads();
        const int r = tid & 15, q = tid >> 4;   // 16 col-groups x 2 cols
        for (int j = 0; j < 16; j++){
          double ar = P[r*33 + 2*j], br = P[r*33 + 2*j + 1];
          double invt = sInv[j];
          #pragma unroll
          for (int k = 0; k < 2; k++){
            int c = q*2 + k;
            if (c >= 2*j+2)
              P[r*33+c] += (br*sAA[j][c] - ar*sBB[j][c]) * invt;
          }
          __syncthreads();
        }
        for (int idx = tid; idx < 16*32; idx += 256){
          int r2 = idx >> 5, c = idx & 31;
          int i = i0 + r2;
          if (i < N) A[(size_t)i*N + c0 + c] = P[r2*33+c];
        }
        __syncthreads();
      }
    }
    gridbar(bar, ++ep);

    // ---------------- phase T: trailing rank-32 update ----------------
    if (m > 0){
      double* sPr = sBuf;          // [64][17]  b_i / t_l
      double* sQr = sBuf + 1088;   // [64][17]  a_i
      double* sPc = sBuf + 2176;   // [32][17]  b_j / t_l
      double* sQc = sBuf + 2720;   // [32][17]  a_j
      const int nrt = (m + 63) >> 6;          // row tiles of 64
      const int cw  = (m + 15) >> 4;          // 16 col slices
      for (int item = blockIdx.x; item < nrt*16; item += PF_BLOCKS){
        const int rt = item % nrt, sl = item / nrt;
        const int i0 = tc0 + rt*64;
        const int iend = (i0 + 64 < N) ? (i0 + 64) : N;
        const int j0 = tc0 + sl*cw;
        const int jend = (j0 + cw < N) ? (j0 + cw) : N;
        if (j0 >= jend) continue;
        // stage row-side panel values
        for (int idx = tid; idx < 64*16; idx += 256){
          const int r = idx >> 4, l = idx & 15;
          const int i = i0 + r;
          double a = 0.0, b = 0.0;
          if (i < iend){
            a = A[(size_t)i*N + c0 + 2*l];
            b = A[(size_t)i*N + c0 + 2*l + 1];
          }
          sQr[r*17+l] = a;
          sPr[r*17+l] = b * sInv[l];
        }
        __syncthreads();
        const int ty = tid >> 4, tx = tid & 15;
        for (int jt = j0; jt < jend; jt += 32){
          for (int idx = tid; idx < 32*16; idx += 256){
            const int cc = idx >> 4, l = idx & 15;
            const int jj = jt + cc;
            double a = 0.0, b = 0.0;
            if (jj < jend){
              a = A[(size_t)jj*N + c0 + 2*l];
              b = A[(size_t)jj*N + c0 + 2*l + 1];
            }
            sQc[cc*17+l] = a;
            sPc[cc*17+l] = b * sInv[l];
          }
          __syncthreads();
          double acc[4][2];
          const int ib = i0 + ty*4;
          const int jb = jt + tx*2;
          #pragma unroll
          for (int rr = 0; rr < 4; rr++)
            #pragma unroll
            for (int cc = 0; cc < 2; cc++){
              int i = ib+rr, jx = jb+cc;
              acc[rr][cc] = (i < iend && jx < jend) ? A[(size_t)i*N + jx] : 0.0;
            }
          #pragma unroll
          for (int l = 0; l < 16; l++){
            double pr[4], qr[4], pc[2], qc[2];
            #pragma unroll
            for (int rr = 0; rr < 4; rr++){ pr[rr] = sPr[(ty*4+rr)*17+l]; qr[rr] = sQr[(ty*4+rr)*17+l]; }
            #pragma unroll
            for (int cc = 0; cc < 2; cc++){ pc[cc] = sPc[(tx*2+cc)*17+l]; qc[cc] = sQc[(tx*2+cc)*17+l]; }
            #pragma unroll
            for (int rr = 0; rr < 4; rr++)
              #pragma unroll
              for (int cc = 0; cc < 2; cc++)
                acc[rr][cc] += pr[rr]*qc[cc] - qr[rr]*pc[cc];
          }
          #pragma unroll
          for (int rr = 0; rr < 4; rr++)
            #pragma unroll
            for (int cc = 0; cc < 2; cc++){
              int i = ib+rr, jx = jb+cc;
              if (i < iend && jx < jend) A[(size_t)i*N + jx] = acc[rr][cc];
            }
          __syncthreads();
        }
      }
    }
    gridbar(bar, ++ep);
  }

  if (blockIdx.x == 0 && tid == 0){
    outp[0] = (float)lsgn;
    outp[1] = (float)(lsum + logJ[0]);
  }
}

// ---------------------------------------------------------------------------
extern "C" void kernel_launch(void* const* d_in, const int* in_sizes, int n_in,
                              void* d_out, int out_size, void* d_ws, size_t ws_size,
                              hipStream_t stream){
  (void)in_sizes; (void)n_in; (void)out_size; (void)ws_size;
  const float* x   = (const float*)d_in[0];
  const float* Fvv = (const float*)d_in[1];
  const float* Fhh = (const float*)d_in[2];
  const float* w1[4] = {(const float*)d_in[3], (const float*)d_in[7],
                        (const float*)d_in[11], (const float*)d_in[15]};
  const float* b1[4] = {(const float*)d_in[4], (const float*)d_in[8],
                        (const float*)d_in[12], (const float*)d_in[16]};
  const float* w2[4] = {(const float*)d_in[5], (const float*)d_in[9],
                        (const float*)d_in[13], (const float*)d_in[17]};
  const float* b2[3] = {(const float*)d_in[6], (const float*)d_in[10],
                        (const float*)d_in[14]};

  char* ws = (char*)d_ws;
  unsigned* bar  = (unsigned*)(ws + 0);         // tree barrier, 0..1215
  double* logJa  = (double*)(ws + 1280);
  int*    nidx   = (int*)(ws + 1536);
  const size_t CB = 589824;  // 64*2304*4
  float* tbuf  = (float*)(ws + 8192);
  float* ybuf  = (float*)(ws + 8192 + CB);
  float* hbuf0 = (float*)(ws + 8192 + 2*CB);
  float* hbuf1 = (float*)(ws + 8192 + 3*CB);
  double* A    = (double*)(ws + 8192 + 4*CB);   // offset 2367488, 8.79 MB

  hipMemsetAsync(d_ws, 0, 2048, stream);        // barrier + logJ acc
  k_find_n<<<1,256,0,stream>>>(x, nidx);

  // CNN block 0: t = (h/sqrt(1))/sqrt(2); res repeats 2ch -> 64ch
  k_pre <<<18, 256,0,stream>>>(x, tbuf, 4608, 0, 0.70710678118654752f);
  k_conv<<<576,256,0,stream>>>(tbuf, w1[0], b1[0], nullptr, ybuf, 2, 0, 1, 1.0f);
  k_conv<<<576,256,0,stream>>>(ybuf, w2[0], b2[0], x,      hbuf0, 64, 2, 0, 1.0f);
  // block 1
  k_pre <<<576,256,0,stream>>>(hbuf0, tbuf, 147456, 1, 0.70710678118654752f);
  k_conv<<<576,256,0,stream>>>(tbuf, w1[1], b1[1], nullptr, ybuf, 64, 0, 1, 1.0f);
  k_conv<<<576,256,0,stream>>>(ybuf, w2[1], b2[1], hbuf0,  hbuf1, 64, 1, 0, 1.0f);
  // block 2
  k_pre <<<576,256,0,stream>>>(hbuf1, tbuf, 147456, 1, 0.57735026918962576f);
  k_conv<<<576,256,0,stream>>>(tbuf, w1[2], b1[2], nullptr, ybuf, 64, 0, 1, 1.0f);
  k_conv<<<576,256,0,stream>>>(ybuf, w2[2], b2[2], hbuf1,  hbuf0, 64, 1, 0, 1.0f);
  // block 3 (no b2; fold final 1/sqrt(5) into epilogue)
  k_pre <<<576,256,0,stream>>>(hbuf0, tbuf, 147456, 1, 0.5f);
  k_conv<<<576,256,0,stream>>>(tbuf, w1[3], b1[3], nullptr, ybuf, 64, 0, 1, 1.0f);
  k_conv<<<576,256,0,stream>>>(ybuf, w2[3], nullptr, hbuf0, hbuf1, 64, 1, 0,
                               0.44721359549995794f);

  k_logJ  <<<144,256,0,stream>>>(hbuf1, logJa);
  k_buildA<<<(PF_N*PF_N+255)/256,256,0,stream>>>(Fvv, Fhh, hbuf1, nidx, A);
  k_pf    <<<PF_BLOCKS,256,0,stream>>>(A, bar, logJa, (float*)d_out);
}

// Round 5
// 1423.210 us; speedup vs baseline: 2.4073x; 2.4073x over previous
//
#include <hip/hip_runtime.h>
#include <math.h>

// ---------------------------------------------------------------------------
// HFPS: CNN (4 residual blocks, circular 3x3 conv, 48x48, 64ch) ->
//       A = [[Fvv[n][:,n], Fvh_n],[-Fvh_n^T, Fhh_a]] (1048x1048 skew) ->
//       sign(Pf(A)), log|Pf(A)| + log_J
// Pfaffian via unpivoted blocked skew LDL^T with 2x2 pivots, fp64.
//   Pf = prod(t_p); log|Pf| = sum log|t_p| = 0.5*slogdet(A).
//
// R5 change (R4 post-mortem: counter/flag/tree barriers ALL cost ~35-45 us
// -> the invariant is the per-block agent-scope fences, which compile to
// full per-XCD L2 writeback+invalidate; 32 redundant flushes per XCD per
// barrier serialize ~30 us and destroy all L2 reuse):
//   - ALL A-matrix accesses in k_pf are relaxed agent-scope atomics
//     (sc0/sc1 cache-bypass -> coherent at the memory-side point, same
//     mechanism that already made the barrier FLAGS work across XCDs).
//   - barrier has ZERO fences: __syncthreads drains vmcnt (stores acked at
//     coherence point) before the relaxed flag store; polls are relaxed.
//   Structure otherwise identical to R3 (256 blocks, flag-array barrier,
//   phases D/R/T unchanged) to isolate the fence effect.
//
// Workspace layout:
//   0:    flags[256] (u32 epoch per block)
//   1024: logJ accumulator (double)
//   1088: nidx[1024] (int)
//   8192: tbuf / ybuf / hbuf0 / hbuf1 (4 x 64*2304 fp32)
//   2367488: A (1048*1048 fp64 = 8.79 MB)
// ---------------------------------------------------------------------------

#define NPIX 2304          // 48*48
#define MSZ  4608          // 2*48*48
#define NOCC 1024
#define NHID 24
#define PF_N 1048          // NOCC + 2*NHID
#define PF_BLOCKS 256

__device__ __forceinline__ float gelu_f(float v){
  // jax.nn.gelu approximate=True (tanh form)
  float v3 = v*v*v;
  return 0.5f*v*(1.0f + tanhf(0.7978845608028654f*(v + 0.044715f*v3)));
}

// coherent (cache-bypassing) A accessors: relaxed agent-scope atomics.
// No fences are ever needed around these; they are visible device-wide
// once vmcnt-acked (same mechanism as the barrier flags, proven in R3).
__device__ __forceinline__ double ald(const double* p){
  return __hip_atomic_load(p, __ATOMIC_RELAXED, __HIP_MEMORY_SCOPE_AGENT);
}
__device__ __forceinline__ void ast(double* p, double v){
  __hip_atomic_store(p, v, __ATOMIC_RELAXED, __HIP_MEMORY_SCOPE_AGENT);
}

// ---- occupied-site indices (sorted), x[i]==1.0f exactly ----
__global__ void k_find_n(const float* __restrict__ x, int* __restrict__ nidx){
  __shared__ int cnt[256];
  __shared__ int off[256];
  int t = threadIdx.x;
  int c = 0;
  for (int k = 0; k < 18; k++) c += (x[t*18+k] == 1.0f) ? 1 : 0;
  cnt[t] = c;
  __syncthreads();
  if (t == 0){ int s = 0; for (int q=0;q<256;q++){ off[q]=s; s+=cnt[q]; } }
  __syncthreads();
  int o = off[t];
  for (int k = 0; k < 18; k++){
    int idx = t*18+k;
    if (x[idx] == 1.0f) nidx[o++] = idx;
  }
}

// ---- elementwise pre-op: t = [gelu](h*scale) ----
__global__ void k_pre(const float* __restrict__ in, float* __restrict__ outp,
                      int count, int dogelu, float scale){
  int g = blockIdx.x*256 + threadIdx.x;
  if (g >= count) return;
  float v = in[g]*scale;
  if (dogelu) v = gelu_f(v);
  outp[g] = v;
}

// ---- circular 3x3 conv, 64 out channels, fused bias/gelu/residual/scale ----
__global__ __launch_bounds__(256) void k_conv(const float* __restrict__ in,
      const float* __restrict__ wgt, const float* __restrict__ bias,
      const float* __restrict__ res, float* __restrict__ outp,
      int cin, int resmode, int dogelu, float scale){
  int c = blockIdx.x / 9;
  int p = (blockIdx.x % 9)*256 + threadIdx.x;
  int y = p / 48, x = p - y*48;
  int ym = ((y+47)%48)*48, y0 = y*48, yp = ((y+1)%48)*48;
  int xm = (x+47)%48, xq = (x+1)%48;
  float s = 0.f;
  const float* wp = wgt + c*cin*9;
  for (int ci = 0; ci < cin; ci++){
    const float* b_ = in + ci*NPIX;
    s += b_[ym+xm]*wp[0] + b_[ym+x]*wp[1] + b_[ym+xq]*wp[2]
       + b_[y0+xm]*wp[3] + b_[y0+x]*wp[4] + b_[y0+xq]*wp[5]
       + b_[yp+xm]*wp[6] + b_[yp+x]*wp[7] + b_[yp+xq]*wp[8];
    wp += 9;
  }
  if (bias) s += bias[c];
  if (dogelu) s = gelu_f(s);
  if (resmode == 1) s += res[c*NPIX + p];
  else if (resmode == 2) s += res[(c>>5)*NPIX + p];  // jnp.repeat(res,32,axis=0)
  s *= scale;
  outp[c*NPIX + p] = s;
}

// ---- log_J = sum over channels 48..63 of final h ----
__global__ void k_logJ(const float* __restrict__ hfin, double* __restrict__ acc){
  int g = blockIdx.x*256 + threadIdx.x;   // 144*256 = 36864
  double v = (double)hfin[48*NPIX + g];
  for (int o = 32; o > 0; o >>= 1) v += __shfl_down(v, o, 64);
  __shared__ double wsum[4];
  int lane = threadIdx.x & 63, wv = threadIdx.x >> 6;
  if (lane == 0) wsum[wv] = v;
  __syncthreads();
  if (threadIdx.x == 0) atomicAdd(acc, wsum[0]+wsum[1]+wsum[2]+wsum[3]);
}

// F_vh[m][r] = out[2r + (m>=2304)][m % 2304]
__device__ __forceinline__ double fvh_val(const float* h, int m, int r){
  int s = (m >= NPIX) ? 1 : 0;
  int p = m - s*NPIX;
  return (double)h[(2*r+s)*NPIX + p];
}

// ---- assemble skew matrix A (fp64) ----
__global__ void k_buildA(const float* __restrict__ Fvv, const float* __restrict__ Fhh,
                         const float* __restrict__ hfin, const int* __restrict__ nidx,
                         double* __restrict__ A){
  int g = blockIdx.x*256 + threadIdx.x;
  if (g >= PF_N*PF_N) return;
  int i = g / PF_N, j = g - i*PF_N;
  double v;
  if (i < NOCC){
    int ni = nidx[i];
    if (j < NOCC){
      int nj = nidx[j];
      v = 0.5*((double)Fvv[(size_t)ni*MSZ + nj] - (double)Fvv[(size_t)nj*MSZ + ni]);
    } else {
      v = fvh_val(hfin, ni, j - NOCC);
    }
  } else {
    int r = i - NOCC;
    if (j < NOCC){
      v = -fvh_val(hfin, nidx[j], r);
    } else {
      int r2 = j - NOCC;
      v = 0.5*((double)Fhh[r*NHID + r2] - (double)Fhh[r2*NHID + r]);
    }
  }
  A[g] = v;
}

// ---- fence-free flag-array grid barrier ----
// All data crossing this barrier travels via relaxed agent-scope atomics
// (cache-bypassing, coherent once vmcnt-acked). __syncthreads drains each
// wave's vmcnt before the flag store, so ordering holds with NO fences
// (and therefore no L2 writeback/invalidate storms).
__device__ __forceinline__ void gridbar(unsigned* flags, unsigned ep){
  __syncthreads();                 // each wave: s_waitcnt vmcnt(0) + barrier
  const int tid = threadIdx.x;
  if (tid == 0){
    asm volatile("" ::: "memory");
    __builtin_amdgcn_s_waitcnt(0);
    __hip_atomic_store(&flags[blockIdx.x], ep, __ATOMIC_RELAXED,
                       __HIP_MEMORY_SCOPE_AGENT);
  }
  if (tid < 64){
    for (;;){
      unsigned v0 = __hip_atomic_load(&flags[tid      ], __ATOMIC_RELAXED, __HIP_MEMORY_SCOPE_AGENT);
      unsigned v1 = __hip_atomic_load(&flags[tid +  64], __ATOMIC_RELAXED, __HIP_MEMORY_SCOPE_AGENT);
      unsigned v2 = __hip_atomic_load(&flags[tid + 128], __ATOMIC_RELAXED, __HIP_MEMORY_SCOPE_AGENT);
      unsigned v3 = __hip_atomic_load(&flags[tid + 192], __ATOMIC_RELAXED, __HIP_MEMORY_SCOPE_AGENT);
      bool ok = (v0 >= ep) & (v1 >= ep) & (v2 >= ep) & (v3 >= ep);
      if (__all(ok)) break;
      __builtin_amdgcn_s_sleep(1);
    }
    asm volatile("" ::: "memory");
  }
  __syncthreads();
}

// ---- blocked skew LDL^T (2x2 pivots, panel=32 cols), Pf accumulation ----
// Update rule (pivot step j, pivot rows r0=2j,r1=2j+1):
//   X[i][c] += (b_i*a_c - a_i*b_c)/t   with a_x = X[x][r0], b_x = X[x][r1]
// Phase D: diag 32x32 in LDS (all blocks, redundant) -> sInv, sAA/sBB history.
// Phase R: rows > panel, panel cols, 16-row LDS tiles over blocks.
// Phase T: trailing S += sum_l (b a^T - a b^T)/t_l (rank-32), all blocks.
__global__ __launch_bounds__(256) void k_pf(double* __restrict__ A,
      unsigned* __restrict__ flags, const double* __restrict__ logJ,
      float* __restrict__ outp){
  const int N = PF_N;
  const int tid = threadIdx.x;
  __shared__ double sBuf[3264];     // D[32][34] / P[16][33] / T-phase tiles
  __shared__ double sAA[16][32];    // a_c^{(j)} history
  __shared__ double sBB[16][32];    // b_c^{(j)} history
  __shared__ double sInv[16];
  __shared__ double sT[16];
  double lsum = 0.0, lsgn = 1.0;    // meaningful in block0/thread0
  unsigned ep = 0;

  for (int c0 = 0; c0 < N; c0 += 32){
    const int w  = (N - c0 < 32) ? (N - c0) : 32;
    const int np = w >> 1;

    // ---------------- phase D: redundant diagonal factorization ----------------
    {
      double* D = sBuf;  // [32][34]
      for (int idx = tid; idx < 32*32; idx += 256){
        int r = idx >> 5, c = idx & 31;
        D[r*34+c] = (r < w && c < w) ? ald(&A[(size_t)(c0+r)*N + c0 + c]) : 0.0;
      }
      __syncthreads();
      for (int j = 0; j < np; j++){
        const int r0 = 2*j, r1 = 2*j+1;
        const double t = D[r0*34+r1];
        const double invt = 1.0 / t;
        if (tid == 0){ sInv[j] = invt; sT[j] = t; }
        if (tid < 32){ sAA[j][tid] = D[tid*34+r0]; sBB[j][tid] = D[tid*34+r1]; }
        // update sub-block rows/cols >= 2j+2 (reads cols r0,r1 only -> no race)
        for (int idx = tid; idx < 32*32; idx += 256){
          int r = idx >> 5, c = idx & 31;
          if (r >= 2*j+2 && c >= 2*j+2 && r < w && c < w){
            double ar = D[r*34+r0], br = D[r*34+r1];
            double ac = D[c*34+r0], bc = D[c*34+r1];
            D[r*34+c] += (br*ac - ar*bc) * invt;
          }
        }
        __syncthreads();
      }
      // parallel pivot log/sign reduction (block 0 only)
      if (blockIdx.x == 0 && tid < 64){
        double lv = 0.0; int sg = 0;
        if (tid < np){ double t = sT[tid]; lv = log(fabs(t)); sg = (t < 0.0) ? 1 : 0; }
        for (int o = 8; o > 0; o >>= 1){
          lv += __shfl_down(lv, o, 64);
          sg += __shfl_down(sg, o, 64);
        }
        if (tid == 0){ lsum += lv; if (sg & 1) lsgn = -lsgn; }
      }
    }

    const int tc0 = c0 + w;
    const int m = N - tc0;

    // ---------------- phase R: panel-column updates for trailing rows ----------
    if (m > 0){               // whenever m>0, w==32 and np==16
      double* P = sBuf;       // [16][33]
      const int nrt = (m + 15) >> 4;
      for (int item = blockIdx.x; item < nrt; item += PF_BLOCKS){
        const int i0 = tc0 + item*16;
        for (int idx = tid; idx < 16*32; idx += 256){
          int r = idx >> 5, c = idx & 31;
          int i = i0 + r;
          P[r*33+c] = (i < N) ? ald(&A[(size_t)i*N + c0 + c]) : 0.0;
        }
        __syncthreads();
        const int r = tid & 15, q = tid >> 4;   // 16 col-groups x 2 cols
        for (int j = 0; j < 16; j++){
          double ar = P[r*33 + 2*j], br = P[r*33 + 2*j + 1];
          double invt = sInv[j];
          #pragma unroll
          for (int k = 0; k < 2; k++){
            int c = q*2 + k;
            if (c >= 2*j+2)
              P[r*33+c] += (br*sAA[j][c] - ar*sBB[j][c]) * invt;
          }
          __syncthreads();
        }
        for (int idx = tid; idx < 16*32; idx += 256){
          int r2 = idx >> 5, c = idx & 31;
          int i = i0 + r2;
          if (i < N) ast(&A[(size_t)i*N + c0 + c], P[r2*33+c]);
        }
        __syncthreads();
      }
    }
    gridbar(flags, ++ep);

    // ---------------- phase T: trailing rank-32 update ----------------
    if (m > 0){
      double* sPr = sBuf;          // [64][17]  b_i / t_l
      double* sQr = sBuf + 1088;   // [64][17]  a_i
      double* sPc = sBuf + 2176;   // [32][17]  b_j / t_l
      double* sQc = sBuf + 2720;   // [32][17]  a_j
      const int nrt = (m + 63) >> 6;          // row tiles of 64
      const int cw  = (m + 15) >> 4;          // 16 col slices
      for (int item = blockIdx.x; item < nrt*16; item += PF_BLOCKS){
        const int rt = item % nrt, sl = item / nrt;
        const int i0 = tc0 + rt*64;
        const int iend = (i0 + 64 < N) ? (i0 + 64) : N;
        const int j0 = tc0 + sl*cw;
        const int jend = (j0 + cw < N) ? (j0 + cw) : N;
        if (j0 >= jend) continue;
        // stage row-side panel values
        for (int idx = tid; idx < 64*16; idx += 256){
          const int r = idx >> 4, l = idx & 15;
          const int i = i0 + r;
          double a = 0.0, b = 0.0;
          if (i < iend){
            a = ald(&A[(size_t)i*N + c0 + 2*l]);
            b = ald(&A[(size_t)i*N + c0 + 2*l + 1]);
          }
          sQr[r*17+l] = a;
          sPr[r*17+l] = b * sInv[l];
        }
        __syncthreads();
        const int ty = tid >> 4, tx = tid & 15;
        for (int jt = j0; jt < jend; jt += 32){
          for (int idx = tid; idx < 32*16; idx += 256){
            const int cc = idx >> 4, l = idx & 15;
            const int jj = jt + cc;
            double a = 0.0, b = 0.0;
            if (jj < jend){
              a = ald(&A[(size_t)jj*N + c0 + 2*l]);
              b = ald(&A[(size_t)jj*N + c0 + 2*l + 1]);
            }
            sQc[cc*17+l] = a;
            sPc[cc*17+l] = b * sInv[l];
          }
          __syncthreads();
          double acc[4][2];
          const int ib = i0 + ty*4;
          const int jb = jt + tx*2;
          #pragma unroll
          for (int rr = 0; rr < 4; rr++)
            #pragma unroll
            for (int cc = 0; cc < 2; cc++){
              int i = ib+rr, jx = jb+cc;
              acc[rr][cc] = (i < iend && jx < jend)
                          ? ald(&A[(size_t)i*N + jx]) : 0.0;
            }
          #pragma unroll
          for (int l = 0; l < 16; l++){
            double pr[4], qr[4], pc[2], qc[2];
            #pragma unroll
            for (int rr = 0; rr < 4; rr++){ pr[rr] = sPr[(ty*4+rr)*17+l]; qr[rr] = sQr[(ty*4+rr)*17+l]; }
            #pragma unroll
            for (int cc = 0; cc < 2; cc++){ pc[cc] = sPc[(tx*2+cc)*17+l]; qc[cc] = sQc[(tx*2+cc)*17+l]; }
            #pragma unroll
            for (int rr = 0; rr < 4; rr++)
              #pragma unroll
              for (int cc = 0; cc < 2; cc++)
                acc[rr][cc] += pr[rr]*qc[cc] - qr[rr]*pc[cc];
          }
          #pragma unroll
          for (int rr = 0; rr < 4; rr++)
            #pragma unroll
            for (int cc = 0; cc < 2; cc++){
              int i = ib+rr, jx = jb+cc;
              if (i < iend && jx < jend) ast(&A[(size_t)i*N + jx], acc[rr][cc]);
            }
          __syncthreads();
        }
      }
    }
    gridbar(flags, ++ep);
  }

  if (blockIdx.x == 0 && tid == 0){
    outp[0] = (float)lsgn;
    outp[1] = (float)(lsum + logJ[0]);
  }
}

// ---------------------------------------------------------------------------
extern "C" void kernel_launch(void* const* d_in, const int* in_sizes, int n_in,
                              void* d_out, int out_size, void* d_ws, size_t ws_size,
                              hipStream_t stream){
  (void)in_sizes; (void)n_in; (void)out_size; (void)ws_size;
  const float* x   = (const float*)d_in[0];
  const float* Fvv = (const float*)d_in[1];
  const float* Fhh = (const float*)d_in[2];
  const float* w1[4] = {(const float*)d_in[3], (const float*)d_in[7],
                        (const float*)d_in[11], (const float*)d_in[15]};
  const float* b1[4] = {(const float*)d_in[4], (const float*)d_in[8],
                        (const float*)d_in[12], (const float*)d_in[16]};
  const float* w2[4] = {(const float*)d_in[5], (const float*)d_in[9],
                        (const float*)d_in[13], (const float*)d_in[17]};
  const float* b2[3] = {(const float*)d_in[6], (const float*)d_in[10],
                        (const float*)d_in[14]};

  char* ws = (char*)d_ws;
  unsigned* flags = (unsigned*)(ws + 0);        // 256 x u32
  double* logJa  = (double*)(ws + 1024);
  int*    nidx   = (int*)(ws + 1088);
  const size_t CB = 589824;  // 64*2304*4
  float* tbuf  = (float*)(ws + 8192);
  float* ybuf  = (float*)(ws + 8192 + CB);
  float* hbuf0 = (float*)(ws + 8192 + 2*CB);
  float* hbuf1 = (float*)(ws + 8192 + 3*CB);
  double* A    = (double*)(ws + 8192 + 4*CB);   // offset 2367488, 8.79 MB

  hipMemsetAsync(d_ws, 0, 2048, stream);        // flags + logJ acc
  k_find_n<<<1,256,0,stream>>>(x, nidx);

  // CNN block 0: t = (h/sqrt(1))/sqrt(2); res repeats 2ch -> 64ch
  k_pre <<<18, 256,0,stream>>>(x, tbuf, 4608, 0, 0.70710678118654752f);
  k_conv<<<576,256,0,stream>>>(tbuf, w1[0], b1[0], nullptr, ybuf, 2, 0, 1, 1.0f);
  k_conv<<<576,256,0,stream>>>(ybuf, w2[0], b2[0], x,      hbuf0, 64, 2, 0, 1.0f);
  // block 1
  k_pre <<<576,256,0,stream>>>(hbuf0, tbuf, 147456, 1, 0.70710678118654752f);
  k_conv<<<576,256,0,stream>>>(tbuf, w1[1], b1[1], nullptr, ybuf, 64, 0, 1, 1.0f);
  k_conv<<<576,256,0,stream>>>(ybuf, w2[1], b2[1], hbuf0,  hbuf1, 64, 1, 0, 1.0f);
  // block 2
  k_pre <<<576,256,0,stream>>>(hbuf1, tbuf, 147456, 1, 0.57735026918962576f);
  k_conv<<<576,256,0,stream>>>(tbuf, w1[2], b1[2], nullptr, ybuf, 64, 0, 1, 1.0f);
  k_conv<<<576,256,0,stream>>>(ybuf, w2[2], b2[2], hbuf1,  hbuf0, 64, 1, 0, 1.0f);
  // block 3 (no b2; fold final 1/sqrt(5) into epilogue)
  k_pre <<<576,256,0,stream>>>(hbuf0, tbuf, 147456, 1, 0.5f);
  k_conv<<<576,256,0,stream>>>(tbuf, w1[3], b1[3], nullptr, ybuf, 64, 0, 1, 1.0f);
  k_conv<<<576,256,0,stream>>>(ybuf, w2[3], nullptr, hbuf0, hbuf1, 64, 1, 0,
                               0.44721359549995794f);

  k_logJ  <<<144,256,0,stream>>>(hbuf1, logJa);
  k_buildA<<<(PF_N*PF_N+255)/256,256,0,stream>>>(Fvv, Fhh, hbuf1, nidx, A);
  k_pf    <<<PF_BLOCKS,256,0,stream>>>(A, flags, logJa, (float*)d_out);
}